// Round 23
// baseline (725.904 us; speedup 1.0000x reference)
//
#include <hip/hip_runtime.h>

#define MBn 2
#define Cn 3
#define Mn 256
#define Nn 256
#define Pn 32
#define IMG   65536      // M*N
#define CIMG  196608     // C*M*N
#define XSZ   393216     // MB*C*M*N
#define ASZ   12582912   // MB*P*C*M*N
#define EPSf  1e-8f
#define NSTEP 10

#define CHW 38   // halo cols (32+6)
#define CHR 70   // halo rows (64+6)
#define CHP 42   // LDS stride
#define CHSZ (CHR * CHW)

#define NCONV 1536   // 8 pg x 32 tiles(64x32) x 6 cm
#define NAUP  6144   // 32 p x 32 tiles(64x32) x 6 cm  (one p per block, 8 outputs/thread)

// ---------------- init: x0 = convT_fil(z, fil) (fil symmetric => conv == convT) ----------------
__global__ __launch_bounds__(256) void k_x0(const float* __restrict__ z, const float* __restrict__ fil,
                                            float* __restrict__ x0, float* __restrict__ x0c) {
    int idx = blockIdx.x * 256 + threadIdx.x;
    if (idx >= XSZ) return;
    int j = idx & 255, i = (idx >> 8) & 255, cm = idx >> 16;
    const float* zc = z + cm * IMG;
    float acc = 0.f;
    #pragma unroll
    for (int u = 0; u < 5; ++u) {
        int ii = i + 2 - u;
        if ((unsigned)ii >= (unsigned)Mn) continue;
        #pragma unroll
        for (int v = 0; v < 5; ++v) {
            int jj = j + 2 - v;
            if ((unsigned)jj >= (unsigned)Nn) continue;
            acc += fil[u * 5 + v] * zc[ii * Nn + jj];
        }
    }
    x0[idx] = acc;
    x0c[idx] = acc;
}

// ---------------- K1: Ba partials = conv_CSC(a, B), 64x32 tile, 4x2/thread, 4 p pipelined ----------------
// blocks 0..1535: pg(8) x tiles(32: 4ti x 8tj) x cm(6). blocks 1536..1537: norm reduce.
__global__ __launch_bounds__(256, 4) void k_conv(const float* __restrict__ a_in, const float* __restrict__ Bg,
                                                 float* __restrict__ Bap,
                                                 const float* __restrict__ part, float* __restrict__ scale2) {
    __shared__ float buf[2][CHR * CHP];
    int blk = blockIdx.x;
    int tid = threadIdx.x;

    if (blk >= NCONV) {           // ---- norm reduce branch ----
        float* red = buf[0];
        int mbi = blk - NCONV;
        float s = 0.f;
        for (int l = tid; l < 3072; l += 256) s += part[mbi * 3072 + l];
        red[tid] = s;
        __syncthreads();
        #pragma unroll
        for (int k = 128; k > 0; k >>= 1) {
            if (tid < k) red[tid] += red[tid + k];
            __syncthreads();
        }
        if (tid == 0) {
            float nrm = sqrtf(red[0]);
            float radius = 0.05f * sqrtf((float)CIMG);
            scale2[mbi] = fminf(1.f, radius / fmaxf(nrm, EPSf));
        }
        return;
    }

    int pg   = blk & 7;
    int tile = (blk >> 3) & 31;     // 4 ti x 8 tj
    int cm   = blk >> 8;            // 0..5
    int c = cm % Cn, mb = cm / Cn;
    int i0 = (tile >> 3) * 64, j0 = (tile & 7) * 32;
    int tx = tid & 15, ty = tid >> 4;

    // hoisted, p-invariant staging coordinates: 11 slots x 256 >= 2660
    int ldsoff[11]; int goff[11]; bool val[11]; bool wm[11];
    #pragma unroll
    for (int k = 0; k < 11; ++k) {
        int l = tid + 256 * k;
        int r = l / CHW, cc = l - r * CHW;
        int gi = i0 + r - 3, gj = j0 + cc - 3;
        wm[k]  = (l < CHSZ);
        val[k] = wm[k] && ((unsigned)gi < (unsigned)Mn) && ((unsigned)gj < (unsigned)Nn);
        ldsoff[k] = r * CHP + cc;
        goff[k]   = gi * Nn + gj;
    }

    const float* abase = a_in + ((size_t)(mb * Pn + pg * 4) * Cn + c) * IMG;
    float rv[11];
    #pragma unroll
    for (int k = 0; k < 11; ++k) rv[k] = val[k] ? abase[goff[k]] : 0.f;

    float acc[8];
    #pragma unroll
    for (int k = 0; k < 8; ++k) acc[k] = 0.f;

    #pragma unroll 1
    for (int pi = 0; pi < 4; ++pi) {
        float* bufc = buf[pi & 1];
        #pragma unroll
        for (int k = 0; k < 11; ++k) if (wm[k]) bufc[ldsoff[k]] = rv[k];
        if (pi < 3) {
            const float* apn = abase + (size_t)(pi + 1) * (Cn * IMG);
            #pragma unroll
            for (int k = 0; k < 11; ++k) rv[k] = val[k] ? apn[goff[k]] : 0.f;
        }
        __syncthreads();
        const float* bq = Bg + ((pg * 4 + pi) * Cn + c) * 49;   // uniform: s_loads
        #pragma unroll
        for (int r = 0; r < 10; ++r) {
            float w[8];
            const float* rowp = bufc + (4 * ty + r) * CHP + 2 * tx;
            #pragma unroll
            for (int k = 0; k < 4; ++k) {
                float2 t = *(const float2*)(rowp + 2 * k);
                w[2 * k] = t.x; w[2 * k + 1] = t.y;
            }
            #pragma unroll
            for (int ri = 0; ri < 4; ++ri) {
                int u = r - ri;
                if (u >= 0 && u <= 6) {
                    #pragma unroll
                    for (int v = 0; v < 7; ++v) {
                        float b = bq[u * 7 + v];       // non-flipped: correlation
                        acc[ri * 2]     += w[v]     * b;
                        acc[ri * 2 + 1] += w[v + 1] * b;
                    }
                }
            }
        }
        // double-buffered: WAR protected by next iteration's barrier
    }
    float* out = Bap + pg * XSZ + cm * IMG;
    #pragma unroll
    for (int ri = 0; ri < 4; ++ri) {
        float2 st; st.x = acc[ri * 2]; st.y = acc[ri * 2 + 1];
        *(float2*)(out + (size_t)(i0 + 4 * ty + ri) * Nn + j0 + 2 * tx) = st;
    }
}

// ---------------- K2: x update + r + v, 2 elems/thread (float2), y2 finalize folded in ----------------
__global__ __launch_bounds__(256) void k_xup(const float* __restrict__ xb, const float* __restrict__ Bap,
                                             const float* __restrict__ y1, const float* __restrict__ y2T,
                                             const float* __restrict__ x0c, const float* __restrict__ fil,
                                             const float* __restrict__ gam1, const float* __restrict__ gam3,
                                             const float* __restrict__ scale2, int step,
                                             float* __restrict__ xa, float* __restrict__ rr,
                                             float* __restrict__ vv) {
    int idx = (blockIdx.x * 256 + threadIdx.x) * 2;
    if (idx >= XSZ) return;
    float g1 = gam1[step];
    int j = idx & 255, i = (idx >> 8) & 255, cm = idx >> 16;   // j even
    int mb = cm / Cn, c = cm - mb * Cn;

    float A = 0.f, Bz = 0.f;      // step 0: y2_prev == 0
    if (step > 0) {
        float g3p = gam3[step - 1];
        float invp = 1.f / (g3p + EPSf);
        float sc = scale2[mb];
        A  = 1.f - g3p * invp * sc;
        Bz = -g3p * (1.f - sc);
    }

    float fl[25];
    #pragma unroll
    for (int k = 0; k < 25; ++k) fl[k] = fil[k];   // uniform s_loads

    // --- y1 Dt term ---
    const float* y10 = y1 + (mb * 2) * CIMG + c * IMG;
    const float* y11 = y10 + CIMG;
    int im1 = (i == 0) ? Mn - 1 : i - 1;
    float2 a0 = *(const float2*)(y10 + im1 * Nn + j);
    float2 b0 = *(const float2*)(y10 + i * Nn + j);
    float2 c0 = *(const float2*)(y11 + i * Nn + j);
    float jm1v = y11[i * Nn + ((j == 0) ? Nn - 1 : j - 1)];
    float dt0 = a0.x - b0.x + jm1v - c0.x;
    float dt1 = a0.y - b0.y + c0.x - c0.y;

    // --- y2T 5x5 stencil for 2 outputs: rv[t] = col j-2+t, t=0..5 ---
    const float* Tc = y2T + cm * IMG;
    float cf0 = 0.f, cf1 = 0.f;
    #pragma unroll
    for (int u = 0; u < 5; ++u) {
        int ii = i + 2 - u;
        if ((unsigned)ii >= (unsigned)Mn) continue;
        const float* rowp = Tc + ii * Nn;
        float rv[6];
        if (j >= 2) { float2 t = *(const float2*)(rowp + j - 2); rv[0] = t.x; rv[1] = t.y; }
        else { rv[0] = 0.f; rv[1] = 0.f; }
        { float2 t = *(const float2*)(rowp + j); rv[2] = t.x; rv[3] = t.y; }
        if (j <= 252) { float2 t = *(const float2*)(rowp + j + 2); rv[4] = t.x; rv[5] = t.y; }
        else { rv[4] = 0.f; rv[5] = 0.f; }
        #pragma unroll
        for (int v = 0; v < 5; ++v) {
            float b = fl[u * 5 + v];
            cf0 += b * rv[4 - v];       // col j   + 2 - v  -> t = 4-v
            cf1 += b * rv[5 - v];       // col j+1 + 2 - v  -> t = 5-v
        }
    }
    float2 x0v = *(const float2*)(x0c + idx);
    cf0 = A * cf0 + Bz * x0v.x;
    cf1 = A * cf1 + Bz * x0v.y;

    // --- Bap sum ---
    float bv0 = 0.f, bv1 = 0.f;
    #pragma unroll
    for (int k = 0; k < 8; ++k) {
        float2 t = *(const float2*)(Bap + (size_t)k * XSZ + idx);
        bv0 += t.x; bv1 += t.y;
    }

    float2 xv = *(const float2*)(xb + idx);
    float xn0 = xv.x - g1 * (xv.x - bv0 + dt0 + cf0);
    float xn1 = xv.y - g1 * (xv.y - bv1 + dt1 + cf1);
    xn0 = fminf(fmaxf(xn0, 0.f), 1.f);
    xn1 = fminf(fmaxf(xn1, 0.f), 1.f);
    { float2 s; s.x = xn0; s.y = xn1; *(float2*)(xa + idx) = s; }
    { float2 s; s.x = xv.x - bv0; s.y = xv.y - bv1; *(float2*)(rr + idx) = s; }
    { float2 s; s.x = 2.f * xn0 - xv.x; s.y = 2.f * xn1 - xv.y; *(float2*)(vv + idx) = s; }
}

// ---------------- K3: a update (64x32 tile, 4x2/thread, one p per block, hoisted staging coords)
//                  + balanced y1/y2 chunk: 64 elements per block, wave-reduce ----------------
__global__ __launch_bounds__(256) void k_aup(const float* __restrict__ a_in, float* __restrict__ a_out,
                                             const float* __restrict__ rr, const float* __restrict__ Bg,
                                             float* __restrict__ y1, float* __restrict__ y2T,
                                             const float* __restrict__ vv, const float* __restrict__ fil,
                                             const float* __restrict__ z,
                                             const float* __restrict__ lam1, const float* __restrict__ lam2,
                                             const float* __restrict__ gam2, const float* __restrict__ gam3,
                                             const float* __restrict__ scale2, int step,
                                             float* __restrict__ partial) {
    __shared__ float rs[CHR * CHP];
    int blk = blockIdx.x;
    int tid = threadIdx.x;

    // ============ part 1: aup tile ============
    {
        int p    = blk & 31;
        int tile = (blk >> 5) & 31;    // 4 ti x 8 tj
        int cm   = blk >> 10;          // 0..5
        int c = cm % Cn, mb = cm / Cn;
        int i0 = (tile >> 3) * 64, j0 = (tile & 7) * 32;
        int tx = tid & 15, ty = tid >> 4;

        int oi = i0 + 4 * ty, oj = j0 + 2 * tx;
        size_t off0 = ((size_t)(mb * Pn + p) * Cn + c) * IMG + (size_t)oi * Nn + oj;

        // issue the a-loads first: latency hides under staging
        float2 cur[4];
        #pragma unroll
        for (int ri = 0; ri < 4; ++ri) cur[ri] = *(const float2*)(a_in + off0 + (size_t)ri * Nn);

        // hoisted staging coordinates (conv-style): 11 slots x 256 >= 2660
        const float* rp = rr + cm * IMG;
        #pragma unroll
        for (int k = 0; k < 11; ++k) {
            int l = tid + 256 * k;
            int r = l / CHW, cc = l - r * CHW;
            int gi = i0 + r - 3, gj = j0 + cc - 3;
            bool wm  = (l < CHSZ);
            bool vok = wm && ((unsigned)gi < (unsigned)Mn) && ((unsigned)gj < (unsigned)Nn);
            float v = vok ? rp[gi * Nn + gj] : 0.f;
            if (wm) rs[r * CHP + cc] = v;
        }
        __syncthreads();

        const float* bp = Bg + (p * Cn + c) * 49;   // uniform: s_loads
        float acc[8];
        #pragma unroll
        for (int k = 0; k < 8; ++k) acc[k] = 0.f;

        #pragma unroll
        for (int r = 0; r < 10; ++r) {
            float w[8];
            const float* rowp = rs + (4 * ty + r) * CHP + 2 * tx;
            #pragma unroll
            for (int k = 0; k < 4; ++k) {
                float2 t = *(const float2*)(rowp + 2 * k);
                w[2 * k] = t.x; w[2 * k + 1] = t.y;
            }
            #pragma unroll
            for (int ri = 0; ri < 4; ++ri) {
                int u = r - ri;
                if (u >= 0 && u <= 6) {
                    #pragma unroll
                    for (int v = 0; v < 7; ++v) {
                        float b = bp[(6 - u) * 7 + (6 - v)];   // flipped: true convolution
                        acc[ri * 2]     += w[v]     * b;
                        acc[ri * 2 + 1] += w[v + 1] * b;
                    }
                }
            }
        }

        float g2 = gam2[step], thr = g2 * lam1[step];
        #pragma unroll
        for (int ri = 0; ri < 4; ++ri) {
            float2 s;
            s.x = cur[ri].x + g2 * acc[ri * 2];
            s.y = cur[ri].y + g2 * acc[ri * 2 + 1];
            s.x = copysignf(fmaxf(fabsf(s.x) - thr, 0.f), s.x);
            s.y = copysignf(fmaxf(fabsf(s.y) - thr, 0.f), s.y);
            *(float2*)(a_out + off0 + (size_t)ri * Nn) = s;
        }
    }

    // ============ part 2: y1/y2 64-element chunk, one wave, shfl-reduce (no barriers) ============
    if (tid >= 64) return;
    {
        int idx = blk * 64 + tid;
        float g3 = gam3[step], l2v = lam2[step];
        int j = idx & 255, i = (idx >> 8) & 255, cm = idx >> 16;
        int mb = cm / Cn, c = cm - mb * Cn;
        const float* vc = vv + cm * IMG;

        float A = 0.f, Bz = 0.f;      // step 0: y2_prev == 0
        if (step > 0) {
            float g3p = gam3[step - 1];
            float invp = 1.f / (g3p + EPSf);
            float sc = scale2[mb];
            A  = 1.f - g3p * invp * sc;
            Bz = -g3p * (1.f - sc);
        }

        int ip1 = (i == Mn - 1) ? 0 : i + 1;
        int jp1 = (j == Nn - 1) ? 0 : j + 1;
        float vij = vc[i * Nn + j];
        float d0 = vc[ip1 * Nn + j] - vij;
        float d1 = vc[i * Nn + jp1] - vij;
        float* y10 = y1 + (mb * 2) * CIMG + c * IMG + i * Nn + j;
        float* y11 = y10 + CIMG;
        float t0 = *y10 + g3 * d0;
        float t1 = *y11 + g3 * d1;
        float inv = 1.f / (g3 + EPSf);
        float w0 = t0 * inv, w1 = t1 * inv;
        float nrm = sqrtf(w0 * w0 + w1 * w1);
        float fac = fmaxf(1.f - (l2v * inv) / fmaxf(nrm, EPSf), 0.f);
        *y10 = t0 - g3 * (w0 * fac);
        *y11 = t1 - g3 * (w1 * fac);

        float cf = 0.f;
        #pragma unroll
        for (int u = 0; u < 5; ++u) {
            int ii2 = i + u - 2;
            if ((unsigned)ii2 >= (unsigned)Mn) continue;
            #pragma unroll
            for (int v = 0; v < 5; ++v) {
                int jj2 = j + v - 2;
                if ((unsigned)jj2 >= (unsigned)Nn) continue;
                cf += fil[u * 5 + v] * vc[ii2 * Nn + jj2];
            }
        }
        float zv = z[idx];
        float t = A * y2T[idx] + Bz * zv + g3 * cf;
        y2T[idx] = t;
        float d = t * inv - zv;
        float d2 = d * d;
        #pragma unroll
        for (int off = 32; off > 0; off >>= 1) d2 += __shfl_down(d2, off, 64);
        if (tid == 0) partial[blk] = d2;
    }
}

extern "C" void kernel_launch(void* const* d_in, const int* in_sizes, int n_in,
                              void* d_out, int out_size, void* d_ws, size_t ws_size,
                              hipStream_t stream) {
    const float* z      = (const float*)d_in[0];
    const float* a_init = (const float*)d_in[1];
    const float* B      = (const float*)d_in[2];
    const float* fil    = (const float*)d_in[3];
    const float* lam1   = (const float*)d_in[4];
    const float* lam2   = (const float*)d_in[5];
    const float* gam1   = (const float*)d_in[6];
    const float* gam2   = (const float*)d_in[7];
    const float* gam3   = (const float*)d_in[8];

    float* ws = (float*)d_ws;
    float* a      = ws;                    // ASZ
    float* xA     = a + ASZ;               // XSZ
    float* xB     = xA + XSZ;              // XSZ
    float* x0c    = xB + XSZ;              // XSZ (persistent conv_fil(z))
    float* Bap    = x0c + XSZ;             // 8*XSZ
    float* rr     = Bap + 8 * XSZ;         // XSZ
    float* vv     = rr + XSZ;              // XSZ
    float* y1     = vv + XSZ;              // 2*XSZ
    float* y2T    = y1 + 2 * XSZ;          // XSZ (pre-finalize accumulator T_s)
    float* part   = y2T + XSZ;             // 6144
    float* scale2 = part + 6144;           // 2

    // init
    hipMemsetAsync(y1, 0, (size_t)2 * XSZ * sizeof(float), stream);
    hipMemsetAsync(part, 0, 6144 * sizeof(float), stream);
    k_x0<<<XSZ / 256, 256, 0, stream>>>(z, fil, xA, x0c);

    float* xin = xA;
    float* xout = xB;
    for (int s = 0; s < NSTEP; ++s) {
        const float* a_src = (s == 0) ? a_init : a;
        k_conv<<<NCONV + 2, 256, 0, stream>>>(a_src, B, Bap, part, scale2);
        k_xup<<<XSZ / 512, 256, 0, stream>>>(xin, Bap, y1, y2T, x0c, fil, gam1, gam3, scale2, s,
                                             xout, rr, vv);
        if (s < NSTEP - 1) {
            k_aup<<<NAUP, 256, 0, stream>>>(a_src, a, rr, B, y1, y2T, vv, fil, z,
                                            lam1, lam2, gam2, gam3, scale2, s, part);
        }
        float* t = xin; xin = xout; xout = t;
    }

    hipMemcpyAsync(d_out, xin, (size_t)XSZ * sizeof(float), hipMemcpyDeviceToDevice, stream);
}

// Round 24
// 684.954 us; speedup vs baseline: 1.0598x; 1.0598x over previous
//
#include <hip/hip_runtime.h>

#define MBn 2
#define Cn 3
#define Mn 256
#define Nn 256
#define Pn 32
#define IMG   65536      // M*N
#define CIMG  196608     // C*M*N
#define XSZ   393216     // MB*C*M*N
#define ASZ   12582912   // MB*P*C*M*N
#define EPSf  1e-8f
#define NSTEP 10

#define CHW 38   // halo cols (32+6)
#define CHR 70   // halo rows (64+6)
#define CHP 42   // LDS stride
#define CHSZ (CHR * CHW)

#define NCONV 1536   // 8 pg x 32 tiles(64x32) x 6 cm
#define NAUP  6144   // 32 p x 32 tiles(64x32) x 6 cm  (one p per block, 8 outputs/thread)

// ---------------- init: x0 = convT_fil(z, fil) (fil symmetric => conv == convT) ----------------
__global__ __launch_bounds__(256) void k_x0(const float* __restrict__ z, const float* __restrict__ fil,
                                            float* __restrict__ x0, float* __restrict__ x0c) {
    int idx = blockIdx.x * 256 + threadIdx.x;
    if (idx >= XSZ) return;
    int j = idx & 255, i = (idx >> 8) & 255, cm = idx >> 16;
    const float* zc = z + cm * IMG;
    float acc = 0.f;
    #pragma unroll
    for (int u = 0; u < 5; ++u) {
        int ii = i + 2 - u;
        if ((unsigned)ii >= (unsigned)Mn) continue;
        #pragma unroll
        for (int v = 0; v < 5; ++v) {
            int jj = j + 2 - v;
            if ((unsigned)jj >= (unsigned)Nn) continue;
            acc += fil[u * 5 + v] * zc[ii * Nn + jj];
        }
    }
    x0[idx] = acc;
    x0c[idx] = acc;
}

// ---------------- K1: Ba partials = conv_CSC(a, B), 64x32 tile, 4x2/thread, 4 p pipelined ----------------
// blocks 0..1535: pg(8) x tiles(32: 4ti x 8tj) x cm(6). blocks 1536..1537: norm reduce.
__global__ __launch_bounds__(256, 4) void k_conv(const float* __restrict__ a_in, const float* __restrict__ Bg,
                                                 float* __restrict__ Bap,
                                                 const float* __restrict__ part, float* __restrict__ scale2) {
    __shared__ float buf[2][CHR * CHP];
    int blk = blockIdx.x;
    int tid = threadIdx.x;

    if (blk >= NCONV) {           // ---- norm reduce branch ----
        float* red = buf[0];
        int mbi = blk - NCONV;
        float s = 0.f;
        for (int l = tid; l < 768; l += 256) s += part[mbi * 768 + l];
        red[tid] = s;
        __syncthreads();
        #pragma unroll
        for (int k = 128; k > 0; k >>= 1) {
            if (tid < k) red[tid] += red[tid + k];
            __syncthreads();
        }
        if (tid == 0) {
            float nrm = sqrtf(red[0]);
            float radius = 0.05f * sqrtf((float)CIMG);
            scale2[mbi] = fminf(1.f, radius / fmaxf(nrm, EPSf));
        }
        return;
    }

    int pg   = blk & 7;
    int tile = (blk >> 3) & 31;     // 4 ti x 8 tj
    int cm   = blk >> 8;            // 0..5
    int c = cm % Cn, mb = cm / Cn;
    int i0 = (tile >> 3) * 64, j0 = (tile & 7) * 32;
    int tx = tid & 15, ty = tid >> 4;

    // hoisted, p-invariant staging coordinates: 11 slots x 256 >= 2660
    int ldsoff[11]; int goff[11]; bool val[11]; bool wm[11];
    #pragma unroll
    for (int k = 0; k < 11; ++k) {
        int l = tid + 256 * k;
        int r = l / CHW, cc = l - r * CHW;
        int gi = i0 + r - 3, gj = j0 + cc - 3;
        wm[k]  = (l < CHSZ);
        val[k] = wm[k] && ((unsigned)gi < (unsigned)Mn) && ((unsigned)gj < (unsigned)Nn);
        ldsoff[k] = r * CHP + cc;
        goff[k]   = gi * Nn + gj;
    }

    const float* abase = a_in + ((size_t)(mb * Pn + pg * 4) * Cn + c) * IMG;
    float rv[11];
    #pragma unroll
    for (int k = 0; k < 11; ++k) rv[k] = val[k] ? abase[goff[k]] : 0.f;

    float acc[8];
    #pragma unroll
    for (int k = 0; k < 8; ++k) acc[k] = 0.f;

    #pragma unroll 1
    for (int pi = 0; pi < 4; ++pi) {
        float* bufc = buf[pi & 1];
        #pragma unroll
        for (int k = 0; k < 11; ++k) if (wm[k]) bufc[ldsoff[k]] = rv[k];
        if (pi < 3) {
            const float* apn = abase + (size_t)(pi + 1) * (Cn * IMG);
            #pragma unroll
            for (int k = 0; k < 11; ++k) rv[k] = val[k] ? apn[goff[k]] : 0.f;
        }
        __syncthreads();
        const float* bq = Bg + ((pg * 4 + pi) * Cn + c) * 49;   // uniform: s_loads
        #pragma unroll
        for (int r = 0; r < 10; ++r) {
            float w[8];
            const float* rowp = bufc + (4 * ty + r) * CHP + 2 * tx;
            #pragma unroll
            for (int k = 0; k < 4; ++k) {
                float2 t = *(const float2*)(rowp + 2 * k);
                w[2 * k] = t.x; w[2 * k + 1] = t.y;
            }
            #pragma unroll
            for (int ri = 0; ri < 4; ++ri) {
                int u = r - ri;
                if (u >= 0 && u <= 6) {
                    #pragma unroll
                    for (int v = 0; v < 7; ++v) {
                        float b = bq[u * 7 + v];       // non-flipped: correlation
                        acc[ri * 2]     += w[v]     * b;
                        acc[ri * 2 + 1] += w[v + 1] * b;
                    }
                }
            }
        }
        // double-buffered: WAR protected by next iteration's barrier
    }
    float* out = Bap + pg * XSZ + cm * IMG;
    #pragma unroll
    for (int ri = 0; ri < 4; ++ri) {
        float2 st; st.x = acc[ri * 2]; st.y = acc[ri * 2 + 1];
        *(float2*)(out + (size_t)(i0 + 4 * ty + ri) * Nn + j0 + 2 * tx) = st;
    }
}

// ---------------- K2: x update + r + v, 2 elems/thread (float2), y2 finalize folded in ----------------
__global__ __launch_bounds__(256) void k_xup(const float* __restrict__ xb, const float* __restrict__ Bap,
                                             const float* __restrict__ y1, const float* __restrict__ y2T,
                                             const float* __restrict__ x0c, const float* __restrict__ fil,
                                             const float* __restrict__ gam1, const float* __restrict__ gam3,
                                             const float* __restrict__ scale2, int step,
                                             float* __restrict__ xa, float* __restrict__ rr,
                                             float* __restrict__ vv) {
    int idx = (blockIdx.x * 256 + threadIdx.x) * 2;
    if (idx >= XSZ) return;
    float g1 = gam1[step];
    int j = idx & 255, i = (idx >> 8) & 255, cm = idx >> 16;   // j even
    int mb = cm / Cn, c = cm - mb * Cn;

    float A = 0.f, Bz = 0.f;      // step 0: y2_prev == 0
    if (step > 0) {
        float g3p = gam3[step - 1];
        float invp = 1.f / (g3p + EPSf);
        float sc = scale2[mb];
        A  = 1.f - g3p * invp * sc;
        Bz = -g3p * (1.f - sc);
    }

    float fl[25];
    #pragma unroll
    for (int k = 0; k < 25; ++k) fl[k] = fil[k];   // uniform s_loads

    // --- y1 Dt term ---
    const float* y10 = y1 + (mb * 2) * CIMG + c * IMG;
    const float* y11 = y10 + CIMG;
    int im1 = (i == 0) ? Mn - 1 : i - 1;
    float2 a0 = *(const float2*)(y10 + im1 * Nn + j);
    float2 b0 = *(const float2*)(y10 + i * Nn + j);
    float2 c0 = *(const float2*)(y11 + i * Nn + j);
    float jm1v = y11[i * Nn + ((j == 0) ? Nn - 1 : j - 1)];
    float dt0 = a0.x - b0.x + jm1v - c0.x;
    float dt1 = a0.y - b0.y + c0.x - c0.y;

    // --- y2T 5x5 stencil for 2 outputs: rv[t] = col j-2+t, t=0..5 ---
    const float* Tc = y2T + cm * IMG;
    float cf0 = 0.f, cf1 = 0.f;
    #pragma unroll
    for (int u = 0; u < 5; ++u) {
        int ii = i + 2 - u;
        if ((unsigned)ii >= (unsigned)Mn) continue;
        const float* rowp = Tc + ii * Nn;
        float rv[6];
        if (j >= 2) { float2 t = *(const float2*)(rowp + j - 2); rv[0] = t.x; rv[1] = t.y; }
        else { rv[0] = 0.f; rv[1] = 0.f; }
        { float2 t = *(const float2*)(rowp + j); rv[2] = t.x; rv[3] = t.y; }
        if (j <= 252) { float2 t = *(const float2*)(rowp + j + 2); rv[4] = t.x; rv[5] = t.y; }
        else { rv[4] = 0.f; rv[5] = 0.f; }
        #pragma unroll
        for (int v = 0; v < 5; ++v) {
            float b = fl[u * 5 + v];
            cf0 += b * rv[4 - v];       // col j   + 2 - v  -> t = 4-v
            cf1 += b * rv[5 - v];       // col j+1 + 2 - v  -> t = 5-v
        }
    }
    float2 x0v = *(const float2*)(x0c + idx);
    cf0 = A * cf0 + Bz * x0v.x;
    cf1 = A * cf1 + Bz * x0v.y;

    // --- Bap sum ---
    float bv0 = 0.f, bv1 = 0.f;
    #pragma unroll
    for (int k = 0; k < 8; ++k) {
        float2 t = *(const float2*)(Bap + (size_t)k * XSZ + idx);
        bv0 += t.x; bv1 += t.y;
    }

    float2 xv = *(const float2*)(xb + idx);
    float xn0 = xv.x - g1 * (xv.x - bv0 + dt0 + cf0);
    float xn1 = xv.y - g1 * (xv.y - bv1 + dt1 + cf1);
    xn0 = fminf(fmaxf(xn0, 0.f), 1.f);
    xn1 = fminf(fmaxf(xn1, 0.f), 1.f);
    { float2 s; s.x = xn0; s.y = xn1; *(float2*)(xa + idx) = s; }
    { float2 s; s.x = xv.x - bv0; s.y = xv.y - bv1; *(float2*)(rr + idx) = s; }
    { float2 s; s.x = 2.f * xn0 - xv.x; s.y = 2.f * xn1 - xv.y; *(float2*)(vv + idx) = s; }
}

// ---------------- K3: a update (64x32 tile, 4x2/thread, one p per block, hoisted staging coords)
//                  + sequential y1/y2 chunk on blocks 0..1535 ----------------
__global__ __launch_bounds__(256) void k_aup(const float* __restrict__ a_in, float* __restrict__ a_out,
                                             const float* __restrict__ rr, const float* __restrict__ Bg,
                                             float* __restrict__ y1, float* __restrict__ y2T,
                                             const float* __restrict__ vv, const float* __restrict__ fil,
                                             const float* __restrict__ z,
                                             const float* __restrict__ lam1, const float* __restrict__ lam2,
                                             const float* __restrict__ gam2, const float* __restrict__ gam3,
                                             const float* __restrict__ scale2, int step,
                                             float* __restrict__ partial) {
    __shared__ float rs[CHR * CHP];
    int blk = blockIdx.x;
    int tid = threadIdx.x;

    // ============ part 1: aup tile ============
    {
        int p    = blk & 31;
        int tile = (blk >> 5) & 31;    // 4 ti x 8 tj
        int cm   = blk >> 10;          // 0..5
        int c = cm % Cn, mb = cm / Cn;
        int i0 = (tile >> 3) * 64, j0 = (tile & 7) * 32;
        int tx = tid & 15, ty = tid >> 4;

        int oi = i0 + 4 * ty, oj = j0 + 2 * tx;
        size_t off0 = ((size_t)(mb * Pn + p) * Cn + c) * IMG + (size_t)oi * Nn + oj;

        // issue the a-loads first: latency hides under staging
        float2 cur[4];
        #pragma unroll
        for (int ri = 0; ri < 4; ++ri) cur[ri] = *(const float2*)(a_in + off0 + (size_t)ri * Nn);

        // hoisted staging coordinates (conv-style): 11 slots x 256 >= 2660
        const float* rp = rr + cm * IMG;
        #pragma unroll
        for (int k = 0; k < 11; ++k) {
            int l = tid + 256 * k;
            int r = l / CHW, cc = l - r * CHW;
            int gi = i0 + r - 3, gj = j0 + cc - 3;
            bool wm  = (l < CHSZ);
            bool vok = wm && ((unsigned)gi < (unsigned)Mn) && ((unsigned)gj < (unsigned)Nn);
            float v = vok ? rp[gi * Nn + gj] : 0.f;
            if (wm) rs[r * CHP + cc] = v;
        }
        __syncthreads();

        const float* bp = Bg + (p * Cn + c) * 49;   // uniform: s_loads
        float acc[8];
        #pragma unroll
        for (int k = 0; k < 8; ++k) acc[k] = 0.f;

        #pragma unroll
        for (int r = 0; r < 10; ++r) {
            float w[8];
            const float* rowp = rs + (4 * ty + r) * CHP + 2 * tx;
            #pragma unroll
            for (int k = 0; k < 4; ++k) {
                float2 t = *(const float2*)(rowp + 2 * k);
                w[2 * k] = t.x; w[2 * k + 1] = t.y;
            }
            #pragma unroll
            for (int ri = 0; ri < 4; ++ri) {
                int u = r - ri;
                if (u >= 0 && u <= 6) {
                    #pragma unroll
                    for (int v = 0; v < 7; ++v) {
                        float b = bp[(6 - u) * 7 + (6 - v)];   // flipped: true convolution
                        acc[ri * 2]     += w[v]     * b;
                        acc[ri * 2 + 1] += w[v + 1] * b;
                    }
                }
            }
        }

        float g2 = gam2[step], thr = g2 * lam1[step];
        #pragma unroll
        for (int ri = 0; ri < 4; ++ri) {
            float2 s;
            s.x = cur[ri].x + g2 * acc[ri * 2];
            s.y = cur[ri].y + g2 * acc[ri * 2 + 1];
            s.x = copysignf(fmaxf(fabsf(s.x) - thr, 0.f), s.x);
            s.y = copysignf(fmaxf(fabsf(s.y) - thr, 0.f), s.y);
            *(float2*)(a_out + off0 + (size_t)ri * Nn) = s;
        }
    }

    // ============ part 2: y1/y2 chunk (blocks 0..1535 only) ============
    if (blk >= XSZ / 256) return;
    __syncthreads();               // rs reused as reduction buffer
    {
        float* red = rs;
        int idx = blk * 256 + tid;
        float g3 = gam3[step], l2v = lam2[step];
        int j = idx & 255, i = (idx >> 8) & 255, cm = idx >> 16;
        int mb = cm / Cn, c = cm - mb * Cn;
        const float* vc = vv + cm * IMG;

        float A = 0.f, Bz = 0.f;      // step 0: y2_prev == 0
        if (step > 0) {
            float g3p = gam3[step - 1];
            float invp = 1.f / (g3p + EPSf);
            float sc = scale2[mb];
            A  = 1.f - g3p * invp * sc;
            Bz = -g3p * (1.f - sc);
        }

        int ip1 = (i == Mn - 1) ? 0 : i + 1;
        int jp1 = (j == Nn - 1) ? 0 : j + 1;
        float vij = vc[i * Nn + j];
        float d0 = vc[ip1 * Nn + j] - vij;
        float d1 = vc[i * Nn + jp1] - vij;
        float* y10 = y1 + (mb * 2) * CIMG + c * IMG + i * Nn + j;
        float* y11 = y10 + CIMG;
        float t0 = *y10 + g3 * d0;
        float t1 = *y11 + g3 * d1;
        float inv = 1.f / (g3 + EPSf);
        float w0 = t0 * inv, w1 = t1 * inv;
        float nrm = sqrtf(w0 * w0 + w1 * w1);
        float fac = fmaxf(1.f - (l2v * inv) / fmaxf(nrm, EPSf), 0.f);
        *y10 = t0 - g3 * (w0 * fac);
        *y11 = t1 - g3 * (w1 * fac);

        float cf = 0.f;
        #pragma unroll
        for (int u = 0; u < 5; ++u) {
            int ii2 = i + u - 2;
            if ((unsigned)ii2 >= (unsigned)Mn) continue;
            #pragma unroll
            for (int v = 0; v < 5; ++v) {
                int jj2 = j + v - 2;
                if ((unsigned)jj2 >= (unsigned)Nn) continue;
                cf += fil[u * 5 + v] * vc[ii2 * Nn + jj2];
            }
        }
        float zv = z[idx];
        float t = A * y2T[idx] + Bz * zv + g3 * cf;
        y2T[idx] = t;
        float d = t * inv - zv;
        red[tid] = d * d;
        __syncthreads();
        #pragma unroll
        for (int s = 128; s > 0; s >>= 1) {
            if (tid < s) red[tid] += red[tid + s];
            __syncthreads();
        }
        if (tid == 0) partial[blk] = red[0];
    }
}

extern "C" void kernel_launch(void* const* d_in, const int* in_sizes, int n_in,
                              void* d_out, int out_size, void* d_ws, size_t ws_size,
                              hipStream_t stream) {
    const float* z      = (const float*)d_in[0];
    const float* a_init = (const float*)d_in[1];
    const float* B      = (const float*)d_in[2];
    const float* fil    = (const float*)d_in[3];
    const float* lam1   = (const float*)d_in[4];
    const float* lam2   = (const float*)d_in[5];
    const float* gam1   = (const float*)d_in[6];
    const float* gam2   = (const float*)d_in[7];
    const float* gam3   = (const float*)d_in[8];

    float* ws = (float*)d_ws;
    float* a      = ws;                    // ASZ
    float* xA     = a + ASZ;               // XSZ
    float* xB     = xA + XSZ;              // XSZ
    float* x0c    = xB + XSZ;              // XSZ (persistent conv_fil(z))
    float* Bap    = x0c + XSZ;             // 8*XSZ
    float* rr     = Bap + 8 * XSZ;         // XSZ
    float* vv     = rr + XSZ;              // XSZ
    float* y1     = vv + XSZ;              // 2*XSZ
    float* y2T    = y1 + 2 * XSZ;          // XSZ (pre-finalize accumulator T_s)
    float* part   = y2T + XSZ;             // 1536
    float* scale2 = part + 1536;           // 2

    // init
    hipMemsetAsync(y1, 0, (size_t)2 * XSZ * sizeof(float), stream);
    hipMemsetAsync(part, 0, 1536 * sizeof(float), stream);
    k_x0<<<XSZ / 256, 256, 0, stream>>>(z, fil, xA, x0c);

    float* xin = xA;
    float* xout = xB;
    for (int s = 0; s < NSTEP; ++s) {
        const float* a_src = (s == 0) ? a_init : a;
        k_conv<<<NCONV + 2, 256, 0, stream>>>(a_src, B, Bap, part, scale2);
        k_xup<<<XSZ / 512, 256, 0, stream>>>(xin, Bap, y1, y2T, x0c, fil, gam1, gam3, scale2, s,
                                             xout, rr, vv);
        if (s < NSTEP - 1) {
            k_aup<<<NAUP, 256, 0, stream>>>(a_src, a, rr, B, y1, y2T, vv, fil, z,
                                            lam1, lam2, gam2, gam3, scale2, s, part);
        }
        float* t = xin; xin = xout; xout = t;
    }

    hipMemcpyAsync(d_out, xin, (size_t)XSZ * sizeof(float), hipMemcpyDeviceToDevice, stream);
}